// Round 5
// baseline (1079.501 us; speedup 1.0000x reference)
//
#include <hip/hip_runtime.h>
#include <math.h>

#define KD 200
#define CD 352
#define NBP 20
#define NPAN 10
#define LMB 0.01f

__device__ __forceinline__ float4 ld4(const float* p) { return *(const float4*)p; }
__device__ __forceinline__ void st4(float* p, float4 v) { *(float4*)p = v; }

#define FMA4(c,a,u) { c.x=fmaf(-(a),(u).x,c.x); c.y=fmaf(-(a),(u).y,c.y); \
                      c.z=fmaf(-(a),(u).z,c.z); c.w=fmaf(-(a),(u).w,c.w); }

// ---------------- Kernel 1: G = A A^T, R = B A^T (batched, tiled) ----------------
__global__ __launch_bounds__(256) void gemm_gr_kernel(
    const float* __restrict__ A, const float* __restrict__ B,
    float* __restrict__ G, float* __restrict__ R)
{
    __shared__ float As[32][33];
    __shared__ float Bs[32][33];
    const int tid = threadIdx.x;
    const int tx = tid & 15, ty = tid >> 4;
    const int z = blockIdx.z;
    const int b = z >> 1, which = z & 1;
    const float* Xb = (which ? B : A) + (size_t)b * KD * CD;
    const float* Ab = A + (size_t)b * KD * CD;
    float* O = (which ? R : G) + (size_t)b * KD * KD;
    const int tileM = blockIdx.y * 32;
    const int tileN = blockIdx.x * 32;

    const int lrow = tid >> 3;
    const int lc   = (tid & 7) * 4;

    float acc00 = 0.f, acc01 = 0.f, acc10 = 0.f, acc11 = 0.f;
    const int m0 = tileM + ty * 2, m1 = m0 + 1;
    const int n0 = tileN + tx * 2, n1 = n0 + 1;

    for (int kk = 0; kk < CD; kk += 32) {
        const int gm = tileM + lrow;
        const int gn = tileN + lrow;
        float4 va = make_float4(0.f, 0.f, 0.f, 0.f);
        float4 vb = make_float4(0.f, 0.f, 0.f, 0.f);
        if (gm < KD) va = *(const float4*)(Xb + (size_t)gm * CD + kk + lc);
        if (gn < KD) vb = *(const float4*)(Ab + (size_t)gn * CD + kk + lc);
        __syncthreads();
        As[lrow][lc + 0] = va.x; As[lrow][lc + 1] = va.y;
        As[lrow][lc + 2] = va.z; As[lrow][lc + 3] = va.w;
        Bs[lrow][lc + 0] = vb.x; Bs[lrow][lc + 1] = vb.y;
        Bs[lrow][lc + 2] = vb.z; Bs[lrow][lc + 3] = vb.w;
        __syncthreads();
        #pragma unroll
        for (int k = 0; k < 32; ++k) {
            float a0 = As[ty * 2][k], a1 = As[ty * 2 + 1][k];
            float b0 = Bs[tx * 2][k], b1 = Bs[tx * 2 + 1][k];
            acc00 = fmaf(a0, b0, acc00); acc01 = fmaf(a0, b1, acc01);
            acc10 = fmaf(a1, b0, acc10); acc11 = fmaf(a1, b1, acc11);
        }
    }
    if (m0 < KD) {
        if (n0 < KD) O[(size_t)m0 * KD + n0] = acc00;
        if (n1 < KD) O[(size_t)m0 * KD + n1] = acc01;
    }
    if (m1 < KD) {
        if (n0 < KD) O[(size_t)m1 * KD + n0] = acc10;
        if (n1 < KD) O[(size_t)m1 * KD + n1] = acc11;
    }
}

// ---------------- Kernel 2: per-(b,i) Cholesky solve, column-major LDS ----------------
// M is COLUMN-major: element (row r, col c) at M[c*KD + r]. M symmetric SPD.
// Only the lower triangle is maintained/used after factorization starts.
__global__ __launch_bounds__(512, 2) void solve_kernel(
    const float* __restrict__ G, const float* __restrict__ R,
    const float* __restrict__ ex, const float* __restrict__ ey,
    float* __restrict__ out)
{
    __shared__ __align__(16) float M[KD * KD];   // 160,000 B
    __shared__ __align__(16) float rhs[KD + 8];
    __shared__ float invd[KD];                   // 1/L[t][t] per column
    __shared__ float dotb[NBP];
    __shared__ float red[8];

    const int tid = threadIdx.x;
    const int sys = blockIdx.x;
    const int b = sys / KD;
    const int i = sys - b * KD;
    const int bK = b * KD;

    // ---- per-batch scale = max(ex, ey) ----
    float mx = 0.f;
    if (tid < KD) mx = fmaxf(ex[bK + tid], ey[bK + tid]);
    #pragma unroll
    for (int off = 32; off > 0; off >>= 1)
        mx = fmaxf(mx, __shfl_down(mx, off, 64));
    if ((tid & 63) == 0) red[tid >> 6] = mx;

    // ---- load G (symmetric: col-major == row-major copy) ----
    const float* Gb = G + (size_t)b * KD * KD;
    for (int idx = tid; idx < KD * KD / 4; idx += 512)
        st4(&M[idx * 4], ld4(Gb + (size_t)idx * 4));
    const float* Rrow = R + (size_t)b * KD * KD + (size_t)i * KD;
    if (tid < KD) rhs[tid] = Rrow[tid];
    __syncthreads();

    if (tid == 0) {
        float s = red[0];
        #pragma unroll
        for (int w = 1; w < 8; ++w) s = fmaxf(s, red[w]);
        red[0] = s;
    }
    __syncthreads();

    // ---- diagonal regularizer ----
    const float scale = red[0];
    const float eyi = ey[bK + i] / scale;
    const float e2 = sqrtf(eyi);
    if (tid < KD) {
        const float exj = ex[bK + tid] / scale;
        const float e1 = sqrtf(exj);
        const float dn = exj + eyi;
        const float re = e2 - e1;
        M[tid * KD + tid] += LMB * ((re * re + 1.f) / (dn * dn));
    }

    // ======== blocked Cholesky M = L L^T (lower triangle) ========
    for (int p = 0; p < NPAN; ++p) {
        const int p0 = p * NBP, p1 = p0 + NBP;
        __syncthreads();

        // -- Phase 1: wave 0 factorizes the 20x20 diag block + forward-solves rhs --
        if (tid < 64) {
            const int r = tid;
            float d[NBP]; float rv = 0.f;
            if (r < NBP) {
                #pragma unroll
                for (int j = 0; j < NBP; ++j)
                    d[j] = (j <= r) ? M[(p0 + j) * KD + p0 + r]
                                    : M[(p0 + r) * KD + p0 + j];   // mirror (lower is valid)
                rv = rhs[p0 + r];
            }
            #pragma unroll
            for (int c = 0; c < NBP; ++c) {
                const float dcc = __shfl(d[c], c, 64);
                const float linv = rsqrtf(dcc);
                const float zc = __shfl(rv, c, 64) * linv;
                if (r == c) {
                    d[c] = dcc * linv;            // L[c][c] = sqrt(dcc)
                    rv = zc;
                    invd[p0 + c] = linv;
                }
                if (r > c && r < NBP) {
                    const float l = d[c] * linv;  // L[r][c]
                    d[c] = l;
                    rv = fmaf(-l, zc, rv);
                    #pragma unroll
                    for (int j = c + 1; j < NBP; ++j)
                        d[j] = fmaf(-l, __shfl(d[c], j, 64), d[j]);
                }
            }
            if (r < NBP) {
                #pragma unroll
                for (int j = 0; j < NBP; ++j)
                    if (j <= r) M[(p0 + j) * KD + p0 + r] = d[j];
                rhs[p0 + r] = rv;                 // z panel
            }
        }
        __syncthreads();

        if (p1 < KD) {
            // -- Phase 2: L21 rows (register recursion, no barriers) + rhs update --
            const int nb = KD - p1;
            if (tid < nb) {
                const int r = p1 + tid;
                float a[NBP];
                #pragma unroll
                for (int t = 0; t < NBP; ++t) a[t] = M[(p0 + t) * KD + r];
                #pragma unroll
                for (int s = 0; s < NBP; ++s) {
                    const float as = a[s] * invd[p0 + s];
                    a[s] = as;
                    #pragma unroll
                    for (int t = s + 1; t < NBP; ++t)
                        a[t] = fmaf(-as, M[(p0 + s) * KD + p0 + t], a[t]); // bcast L11[t][s]
                }
                float rv = rhs[r];
                #pragma unroll
                for (int t = 0; t < NBP; ++t) {
                    M[(p0 + t) * KD + r] = a[t];
                    rv = fmaf(-a[t], rhs[p0 + t], rv);
                }
                rhs[r] = rv;
            }
            __syncthreads();

            // -- Phase 3: trailing update C -= L21 L21^T (lower triangle tiles) --
            const int cg = tid >> 5, lane = tid & 31;
            for (int jb = p1 + cg * 4; jb < KD; jb += 64) {
                float4 w4[NBP];   // w4[t].{x..w} = L[jb+0..3][t]  (broadcast b128)
                #pragma unroll
                for (int t = 0; t < NBP; ++t)
                    w4[t] = ld4(&M[(p0 + t) * KD + jb]);
                for (int ro = jb + lane * 4; ro < KD; ro += 128) {
                    float4 c0 = ld4(&M[(jb + 0) * KD + ro]);
                    float4 c1 = ld4(&M[(jb + 1) * KD + ro]);
                    float4 c2 = ld4(&M[(jb + 2) * KD + ro]);
                    float4 c3 = ld4(&M[(jb + 3) * KD + ro]);
                    #pragma unroll
                    for (int t = 0; t < NBP; ++t) {
                        const float4 lv = ld4(&M[(p0 + t) * KD + ro]);
                        FMA4(c0, w4[t].x, lv); FMA4(c1, w4[t].y, lv);
                        FMA4(c2, w4[t].z, lv); FMA4(c3, w4[t].w, lv);
                    }
                    st4(&M[(jb + 0) * KD + ro], c0);
                    st4(&M[(jb + 1) * KD + ro], c1);
                    st4(&M[(jb + 2) * KD + ro], c2);
                    st4(&M[(jb + 3) * KD + ro], c3);
                }
            }
        }
    }
    __syncthreads();

    // ======== backward solve x = L^{-T} z ========
    for (int p = NPAN - 1; p >= 0; --p) {
        const int p0 = p * NBP, p1 = p0 + NBP;
        // dots: s_t = sum_{r>=p1} L[r][p0+t] * x[r]
        if (p1 < KD) {
            const int w = tid >> 6, lane = tid & 63;
            for (int t = w; t < NBP; t += 8) {
                float partial = 0.f;
                for (int r = p1 + lane; r < KD; r += 64)
                    partial = fmaf(M[(p0 + t) * KD + r], rhs[r], partial);
                #pragma unroll
                for (int off = 32; off > 0; off >>= 1)
                    partial += __shfl_xor(partial, off, 64);
                if (lane == 0) dotb[t] = partial;
            }
        } else if (tid < NBP) {
            dotb[tid] = 0.f;
        }
        __syncthreads();
        // wave 0: x[p0:p1] = L11^{-T} (z - dots), register-resident
        if (tid < 64) {
            const int s = tid;
            float cL[NBP]; float v = 0.f;
            if (s < NBP) {
                v = rhs[p0 + s] - dotb[s];
                #pragma unroll
                for (int t = 0; t < NBP; ++t)
                    cL[t] = (t >= s) ? M[(p0 + s) * KD + p0 + t] : 0.f;  // L11[t][s]
            }
            #pragma unroll
            for (int t = NBP - 1; t >= 0; --t) {
                const float xt = __shfl(v, t, 64) * invd[p0 + t];
                if (s == t && s < NBP) rhs[p0 + t] = xt;
                if (s < t) v = fmaf(-cL[t], xt, v);
            }
        }
        __syncthreads();
    }

    // ---- store Cxy[b, i, :] ----
    float* Orow = out + (size_t)b * KD * KD + (size_t)i * KD;
    if (tid < KD / 4)
        st4(&Orow[tid * 4], ld4(&rhs[tid * 4]));
}

extern "C" void kernel_launch(void* const* d_in, const int* in_sizes, int n_in,
                              void* d_out, int out_size, void* d_ws, size_t ws_size,
                              hipStream_t stream) {
    const float* A  = (const float*)d_in[0];
    const float* B  = (const float*)d_in[1];
    const float* ex = (const float*)d_in[2];
    const float* ey = (const float*)d_in[3];
    float* out = (float*)d_out;

    float* G = (float*)d_ws;
    float* R = G + 8 * KD * KD;

    dim3 grid1(7, 7, 16);
    gemm_gr_kernel<<<grid1, 256, 0, stream>>>(A, B, G, R);

    solve_kernel<<<1600, 512, 0, stream>>>(G, R, ex, ey, out);
}

// Round 6
// 1042.660 us; speedup vs baseline: 1.0353x; 1.0353x over previous
//
#include <hip/hip_runtime.h>
#include <math.h>

#define KD 200
#define CD 352
#define NBP 20
#define NPAN 10
#define LMB 0.01f

__device__ __forceinline__ float4 ld4(const float* p) { return *(const float4*)p; }
__device__ __forceinline__ void st4(float* p, float4 v) { *(float4*)p = v; }

#define FMA4(c,a,u) { c.x=fmaf(-(a),(u).x,c.x); c.y=fmaf(-(a),(u).y,c.y); \
                      c.z=fmaf(-(a),(u).z,c.z); c.w=fmaf(-(a),(u).w,c.w); }

// ---------------- Kernel 1: G = A A^T, R = B A^T (batched, tiled) ----------------
__global__ __launch_bounds__(256) void gemm_gr_kernel(
    const float* __restrict__ A, const float* __restrict__ B,
    float* __restrict__ G, float* __restrict__ R)
{
    __shared__ float As[32][33];
    __shared__ float Bs[32][33];
    const int tid = threadIdx.x;
    const int tx = tid & 15, ty = tid >> 4;
    const int z = blockIdx.z;
    const int b = z >> 1, which = z & 1;
    const float* Xb = (which ? B : A) + (size_t)b * KD * CD;
    const float* Ab = A + (size_t)b * KD * CD;
    float* O = (which ? R : G) + (size_t)b * KD * KD;
    const int tileM = blockIdx.y * 32;
    const int tileN = blockIdx.x * 32;

    const int lrow = tid >> 3;
    const int lc   = (tid & 7) * 4;

    float acc00 = 0.f, acc01 = 0.f, acc10 = 0.f, acc11 = 0.f;
    const int m0 = tileM + ty * 2, m1 = m0 + 1;
    const int n0 = tileN + tx * 2, n1 = n0 + 1;

    for (int kk = 0; kk < CD; kk += 32) {
        const int gm = tileM + lrow;
        const int gn = tileN + lrow;
        float4 va = make_float4(0.f, 0.f, 0.f, 0.f);
        float4 vb = make_float4(0.f, 0.f, 0.f, 0.f);
        if (gm < KD) va = *(const float4*)(Xb + (size_t)gm * CD + kk + lc);
        if (gn < KD) vb = *(const float4*)(Ab + (size_t)gn * CD + kk + lc);
        __syncthreads();
        As[lrow][lc + 0] = va.x; As[lrow][lc + 1] = va.y;
        As[lrow][lc + 2] = va.z; As[lrow][lc + 3] = va.w;
        Bs[lrow][lc + 0] = vb.x; Bs[lrow][lc + 1] = vb.y;
        Bs[lrow][lc + 2] = vb.z; Bs[lrow][lc + 3] = vb.w;
        __syncthreads();
        #pragma unroll
        for (int k = 0; k < 32; ++k) {
            float a0 = As[ty * 2][k], a1 = As[ty * 2 + 1][k];
            float b0 = Bs[tx * 2][k], b1 = Bs[tx * 2 + 1][k];
            acc00 = fmaf(a0, b0, acc00); acc01 = fmaf(a0, b1, acc01);
            acc10 = fmaf(a1, b0, acc10); acc11 = fmaf(a1, b1, acc11);
        }
    }
    if (m0 < KD) {
        if (n0 < KD) O[(size_t)m0 * KD + n0] = acc00;
        if (n1 < KD) O[(size_t)m0 * KD + n1] = acc01;
    }
    if (m1 < KD) {
        if (n0 < KD) O[(size_t)m1 * KD + n0] = acc10;
        if (n1 < KD) O[(size_t)m1 * KD + n1] = acc11;
    }
}

// ---------------- Kernel 2: per-(b,i) Cholesky solve, column-major LDS ----------------
// M is COLUMN-major: (row r, col c) at M[c*KD + r]. Symmetric SPD; lower triangle only.
// launch_bounds(512,1): LDS already limits to 1 block/CU; allow 256 VGPRs so the
// register arrays (d[20], w4[20], a[20], cL[20]) never spill to scratch.
__global__ __launch_bounds__(512, 1) void solve_kernel(
    const float* __restrict__ G, const float* __restrict__ R,
    const float* __restrict__ ex, const float* __restrict__ ey,
    float* __restrict__ out)
{
    __shared__ __align__(16) float M[KD * KD];   // 160,000 B
    __shared__ __align__(16) float rhs[KD + 8];
    __shared__ float invd[KD];                   // 1/L[t][t] per column
    __shared__ float dotb[NBP];
    __shared__ float red[8];

    const int tid = threadIdx.x;
    const int sys = blockIdx.x;
    const int b = sys / KD;
    const int i = sys - b * KD;
    const int bK = b * KD;

    // ---- per-batch scale = max(ex, ey) ----
    float mx = 0.f;
    if (tid < KD) mx = fmaxf(ex[bK + tid], ey[bK + tid]);
    #pragma unroll
    for (int off = 32; off > 0; off >>= 1)
        mx = fmaxf(mx, __shfl_down(mx, off, 64));
    if ((tid & 63) == 0) red[tid >> 6] = mx;

    // ---- load G (symmetric: col-major == row-major copy) ----
    const float* Gb = G + (size_t)b * KD * KD;
    for (int idx = tid; idx < KD * KD / 4; idx += 512)
        st4(&M[idx * 4], ld4(Gb + (size_t)idx * 4));
    const float* Rrow = R + (size_t)b * KD * KD + (size_t)i * KD;
    if (tid < KD) rhs[tid] = Rrow[tid];
    __syncthreads();

    if (tid == 0) {
        float s = red[0];
        #pragma unroll
        for (int w = 1; w < 8; ++w) s = fmaxf(s, red[w]);
        red[0] = s;
    }
    __syncthreads();

    // ---- diagonal regularizer ----
    const float scale = red[0];
    const float eyi = ey[bK + i] / scale;
    const float e2 = sqrtf(eyi);
    if (tid < KD) {
        const float exj = ex[bK + tid] / scale;
        const float e1 = sqrtf(exj);
        const float dn = exj + eyi;
        const float re = e2 - e1;
        M[tid * KD + tid] += LMB * ((re * re + 1.f) / (dn * dn));
    }

    // ======== blocked Cholesky M = L L^T (lower triangle) ========
    for (int p = 0; p < NPAN; ++p) {
        const int p0 = p * NBP, p1 = p0 + NBP;
        __syncthreads();

        // -- Phase 1: wave 0 factorizes the 20x20 diag block + forward-solves rhs --
        if (tid < 64) {
            const int r = tid;
            float d[NBP]; float rv = 0.f;
            if (r < NBP) {
                #pragma unroll
                for (int j = 0; j < NBP; ++j)
                    d[j] = (j <= r) ? M[(p0 + j) * KD + p0 + r]
                                    : M[(p0 + r) * KD + p0 + j];   // mirror (lower is valid)
                rv = rhs[p0 + r];
            }
            #pragma unroll
            for (int c = 0; c < NBP; ++c) {
                const float dcc = __shfl(d[c], c, 64);
                const float linv = rsqrtf(dcc);
                const float zc = __shfl(rv, c, 64) * linv;
                if (r == c) {
                    d[c] = dcc * linv;            // L[c][c] = sqrt(dcc)
                    rv = zc;
                    invd[p0 + c] = linv;
                }
                if (r > c && r < NBP) {
                    const float l = d[c] * linv;  // L[r][c]
                    d[c] = l;
                    rv = fmaf(-l, zc, rv);
                    #pragma unroll
                    for (int j = c + 1; j < NBP; ++j)
                        d[j] = fmaf(-l, __shfl(d[c], j, 64), d[j]);
                }
            }
            if (r < NBP) {
                #pragma unroll
                for (int j = 0; j < NBP; ++j)
                    if (j <= r) M[(p0 + j) * KD + p0 + r] = d[j];
                rhs[p0 + r] = rv;                 // z panel
            }
        }
        __syncthreads();

        if (p1 < KD) {
            // -- Phase 2: L21 rows (register recursion, float4 broadcast L11 reads) --
            const int nb = KD - p1;
            if (tid < nb) {
                const int r = p1 + tid;
                float a[NBP];
                #pragma unroll
                for (int t = 0; t < NBP; ++t) a[t] = M[(p0 + t) * KD + r];
                #pragma unroll
                for (int s = 0; s < NBP; ++s) {
                    const float as = a[s] * invd[p0 + s];
                    a[s] = as;
                    #pragma unroll
                    for (int q = (s + 1) >> 2; q < 5; ++q) {
                        // L11 column s, rows 4q..4q+3: contiguous in lower triangle
                        const float4 l4 = ld4(&M[(p0 + s) * KD + p0 + 4 * q]); // broadcast
                        if (4*q+0 > s) a[4*q+0] = fmaf(-as, l4.x, a[4*q+0]);
                        if (4*q+1 > s) a[4*q+1] = fmaf(-as, l4.y, a[4*q+1]);
                        if (4*q+2 > s) a[4*q+2] = fmaf(-as, l4.z, a[4*q+2]);
                        if (4*q+3 > s) a[4*q+3] = fmaf(-as, l4.w, a[4*q+3]);
                    }
                }
                float rv = rhs[r];
                #pragma unroll
                for (int t = 0; t < NBP; ++t) {
                    M[(p0 + t) * KD + r] = a[t];
                    rv = fmaf(-a[t], rhs[p0 + t], rv);
                }
                rhs[r] = rv;
            }
            __syncthreads();

            // -- Phase 3: trailing update C -= L21 L21^T (lower triangle tiles) --
            const int cg = tid >> 5, lane = tid & 31;
            for (int jb = p1 + cg * 4; jb < KD; jb += 64) {
                float4 w4[NBP];   // w4[t].{x..w} = L[jb+0..3][t]  (broadcast b128)
                #pragma unroll
                for (int t = 0; t < NBP; ++t)
                    w4[t] = ld4(&M[(p0 + t) * KD + jb]);
                for (int ro = jb + lane * 4; ro < KD; ro += 128) {
                    float4 c0 = ld4(&M[(jb + 0) * KD + ro]);
                    float4 c1 = ld4(&M[(jb + 1) * KD + ro]);
                    float4 c2 = ld4(&M[(jb + 2) * KD + ro]);
                    float4 c3 = ld4(&M[(jb + 3) * KD + ro]);
                    #pragma unroll
                    for (int t = 0; t < NBP; ++t) {
                        const float4 lv = ld4(&M[(p0 + t) * KD + ro]);
                        FMA4(c0, w4[t].x, lv); FMA4(c1, w4[t].y, lv);
                        FMA4(c2, w4[t].z, lv); FMA4(c3, w4[t].w, lv);
                    }
                    st4(&M[(jb + 0) * KD + ro], c0);
                    st4(&M[(jb + 1) * KD + ro], c1);
                    st4(&M[(jb + 2) * KD + ro], c2);
                    st4(&M[(jb + 3) * KD + ro], c3);
                }
            }
        }
    }
    __syncthreads();

    // ======== backward solve x = L^{-T} z ========
    for (int p = NPAN - 1; p >= 0; --p) {
        const int p0 = p * NBP, p1 = p0 + NBP;
        // dots: s_t = sum_{r>=p1} L[r][p0+t] * x[r]
        if (p1 < KD) {
            const int w = tid >> 6, lane = tid & 63;
            for (int t = w; t < NBP; t += 8) {
                float partial = 0.f;
                for (int r = p1 + lane; r < KD; r += 64)
                    partial = fmaf(M[(p0 + t) * KD + r], rhs[r], partial);
                #pragma unroll
                for (int off = 32; off > 0; off >>= 1)
                    partial += __shfl_xor(partial, off, 64);
                if (lane == 0) dotb[t] = partial;
            }
        } else if (tid < NBP) {
            dotb[tid] = 0.f;
        }
        __syncthreads();
        // wave 0: x[p0:p1] = L11^{-T} (z - dots), register-resident
        if (tid < 64) {
            const int s = tid;
            float cL[NBP]; float v = 0.f;
            if (s < NBP) {
                v = rhs[p0 + s] - dotb[s];
                #pragma unroll
                for (int t = 0; t < NBP; ++t)
                    cL[t] = (t >= s) ? M[(p0 + s) * KD + p0 + t] : 0.f;  // L11[t][s]
            }
            #pragma unroll
            for (int t = NBP - 1; t >= 0; --t) {
                const float xt = __shfl(v, t, 64) * invd[p0 + t];
                if (s == t && s < NBP) rhs[p0 + t] = xt;
                if (s < t) v = fmaf(-cL[t], xt, v);
            }
        }
        __syncthreads();
    }

    // ---- store Cxy[b, i, :] ----
    float* Orow = out + (size_t)b * KD * KD + (size_t)i * KD;
    if (tid < KD / 4)
        st4(&Orow[tid * 4], ld4(&rhs[tid * 4]));
}

extern "C" void kernel_launch(void* const* d_in, const int* in_sizes, int n_in,
                              void* d_out, int out_size, void* d_ws, size_t ws_size,
                              hipStream_t stream) {
    const float* A  = (const float*)d_in[0];
    const float* B  = (const float*)d_in[1];
    const float* ex = (const float*)d_in[2];
    const float* ey = (const float*)d_in[3];
    float* out = (float*)d_out;

    float* G = (float*)d_ws;
    float* R = G + 8 * KD * KD;

    dim3 grid1(7, 7, 16);
    gemm_gr_kernel<<<grid1, 256, 0, stream>>>(A, B, G, R);

    solve_kernel<<<1600, 512, 0, stream>>>(G, R, ex, ey, out);
}

// Round 7
// 385.544 us; speedup vs baseline: 2.7999x; 2.7044x over previous
//
#include <hip/hip_runtime.h>
#include <math.h>

#define KD 200
#define CD 352
#define NSYS 8      // systems per block
#define NITER 50    // PCG iterations (rate ~0.76 => ~5e-7 rel)
#define LMB 0.01f

__device__ __forceinline__ float4 ld4(const float* p) { return *(const float4*)p; }
__device__ __forceinline__ void st4(float* p, float4 v) { *(float4*)p = v; }

// ---------------- Kernel 1: G = A A^T, R = B A^T (batched, tiled) ----------------
__global__ __launch_bounds__(256) void gemm_gr_kernel(
    const float* __restrict__ A, const float* __restrict__ B,
    float* __restrict__ G, float* __restrict__ R)
{
    __shared__ float As[32][33];
    __shared__ float Bs[32][33];
    const int tid = threadIdx.x;
    const int tx = tid & 15, ty = tid >> 4;
    const int z = blockIdx.z;
    const int b = z >> 1, which = z & 1;
    const float* Xb = (which ? B : A) + (size_t)b * KD * CD;
    const float* Ab = A + (size_t)b * KD * CD;
    float* O = (which ? R : G) + (size_t)b * KD * KD;
    const int tileM = blockIdx.y * 32;
    const int tileN = blockIdx.x * 32;

    const int lrow = tid >> 3;
    const int lc   = (tid & 7) * 4;

    float acc00 = 0.f, acc01 = 0.f, acc10 = 0.f, acc11 = 0.f;
    const int m0 = tileM + ty * 2, m1 = m0 + 1;
    const int n0 = tileN + tx * 2, n1 = n0 + 1;

    for (int kk = 0; kk < CD; kk += 32) {
        const int gm = tileM + lrow;
        const int gn = tileN + lrow;
        float4 va = make_float4(0.f, 0.f, 0.f, 0.f);
        float4 vb = make_float4(0.f, 0.f, 0.f, 0.f);
        if (gm < KD) va = *(const float4*)(Xb + (size_t)gm * CD + kk + lc);
        if (gn < KD) vb = *(const float4*)(Ab + (size_t)gn * CD + kk + lc);
        __syncthreads();
        As[lrow][lc + 0] = va.x; As[lrow][lc + 1] = va.y;
        As[lrow][lc + 2] = va.z; As[lrow][lc + 3] = va.w;
        Bs[lrow][lc + 0] = vb.x; Bs[lrow][lc + 1] = vb.y;
        Bs[lrow][lc + 2] = vb.z; Bs[lrow][lc + 3] = vb.w;
        __syncthreads();
        #pragma unroll
        for (int k = 0; k < 32; ++k) {
            float a0 = As[ty * 2][k], a1 = As[ty * 2 + 1][k];
            float b0 = Bs[tx * 2][k], b1 = Bs[tx * 2 + 1][k];
            acc00 = fmaf(a0, b0, acc00); acc01 = fmaf(a0, b1, acc01);
            acc10 = fmaf(a1, b0, acc10); acc11 = fmaf(a1, b1, acc11);
        }
    }
    if (m0 < KD) {
        if (n0 < KD) O[(size_t)m0 * KD + n0] = acc00;
        if (n1 < KD) O[(size_t)m0 * KD + n1] = acc01;
    }
    if (m1 < KD) {
        if (n0 < KD) O[(size_t)m1 * KD + n0] = acc10;
        if (n1 < KD) O[(size_t)m1 * KD + n1] = acc11;
    }
}

// ---------------- Kernel 2: batched Jacobi-PCG, 8 systems per block ----------------
// Solves (G_b + lam_i*diag) x_i = r_i for 8 consecutive i per block.
// Matvec: thread (r, half) accumulates q[r][4h..4h+3] over c, reading G column-wise
// (G symmetric -> G[r][c] = Gb[c*KD+r], coalesced over lanes). p/q stride 8 (ld4-able);
// x/r stride 9 (conflict-free for wave-phase stride-8 lane access).
__global__ __launch_bounds__(512) void cg_kernel(
    const float* __restrict__ G, const float* __restrict__ R,
    const float* __restrict__ ex, const float* __restrict__ ey,
    float* __restrict__ out)
{
    __shared__ __align__(16) float p[KD * NSYS];
    __shared__ __align__(16) float q[KD * NSYS];
    __shared__ float xv[KD * 9];
    __shared__ float rv[KD * 9];
    __shared__ float lam[NSYS * KD];
    __shared__ float dinv[NSYS * KD];
    __shared__ float red[8];

    const int tid = threadIdx.x;
    const int blk = blockIdx.x;          // 0..199
    const int b = blk / 25;              // 25 blocks per batch
    const int i0 = (blk - b * 25) * NSYS;
    const int bK = b * KD;
    const float* __restrict__ Gb = G + (size_t)b * KD * KD;

    // ---- scale = max(ex[b,:], ey[b,:]) ----
    float mxv = 0.f;
    if (tid < KD) mxv = fmaxf(ex[bK + tid], ey[bK + tid]);
    #pragma unroll
    for (int off = 32; off > 0; off >>= 1)
        mxv = fmaxf(mxv, __shfl_down(mxv, off, 64));
    if ((tid & 63) == 0) red[tid >> 6] = mxv;
    __syncthreads();
    float scale = red[0];
    #pragma unroll
    for (int wv = 1; wv < 8; ++wv) scale = fmaxf(scale, red[wv]);
    const float inv_scale = 1.0f / scale;

    // ---- lam[s][r] = LMB * D[b, i0+s, r]; dinv = 1/(G[r][r]+lam) ----
    for (int idx = tid; idx < NSYS * KD; idx += 512) {
        const int s = idx / KD, r = idx - s * KD;
        const float eyi = ey[bK + i0 + s] * inv_scale;
        const float exj = ex[bK + r] * inv_scale;
        const float e1 = sqrtf(exj), e2 = sqrtf(eyi);
        const float dn = exj + eyi;
        const float re = e2 - e1;
        const float lm = LMB * ((re * re + 1.0f) / (dn * dn));
        lam[idx] = lm;
        dinv[idx] = 1.0f / (Gb[(size_t)r * KD + r] + lm);
    }
    // ---- rhs & x0 = 0 ----
    for (int idx = tid; idx < NSYS * KD; idx += 512) {
        const int r = idx >> 3, s = idx & 7;
        rv[r * 9 + s] = R[(size_t)(bK + i0 + s) * KD + r];
        xv[r * 9 + s] = 0.f;
    }
    __syncthreads();

    // ---- wave w owns system w: p = z = dinv*r; rz = r.z ----
    const int w = tid >> 6, l = tid & 63;
    float rz = 0.f;
    for (int r = l; r < KD; r += 64) {
        const float rr = rv[r * 9 + w];
        const float z = rr * dinv[w * KD + r];
        p[r * 8 + w] = z;
        rz = fmaf(rr, z, rz);
    }
    #pragma unroll
    for (int off = 1; off < 64; off <<= 1)
        rz += __shfl_xor(rz, off, 64);

    const int mr = tid >> 1;                 // matvec row
    const int sh = (tid & 1) << 2;           // system-half offset: 0 or 4

    // ================= PCG main loop =================
    for (int k = 0; k < NITER; ++k) {
        __syncthreads();                      // p stable for matvec
        if (tid < 2 * KD) {
            const float* __restrict__ gcol = Gb + mr;
            float4 acc = make_float4(0.f, 0.f, 0.f, 0.f);
            #pragma unroll 8
            for (int c = 0; c < KD; ++c) {
                const float gv = gcol[(size_t)c * KD];      // G[mr][c] (symmetric)
                const float4 pv = ld4(&p[c * 8 + sh]);      // broadcast
                acc.x = fmaf(gv, pv.x, acc.x);
                acc.y = fmaf(gv, pv.y, acc.y);
                acc.z = fmaf(gv, pv.z, acc.z);
                acc.w = fmaf(gv, pv.w, acc.w);
            }
            const float4 pr = ld4(&p[mr * 8 + sh]);
            acc.x = fmaf(lam[(sh + 0) * KD + mr], pr.x, acc.x);
            acc.y = fmaf(lam[(sh + 1) * KD + mr], pr.y, acc.y);
            acc.z = fmaf(lam[(sh + 2) * KD + mr], pr.z, acc.z);
            acc.w = fmaf(lam[(sh + 3) * KD + mr], pr.w, acc.w);
            st4(&q[mr * 8 + sh], acc);
        }
        __syncthreads();                      // q ready

        // ---- wave phase (system w): pq, alpha, axpy, rz_new, beta, p-update ----
        float pq = 0.f;
        for (int r = l; r < KD; r += 64)
            pq = fmaf(p[r * 8 + w], q[r * 8 + w], pq);
        #pragma unroll
        for (int off = 1; off < 64; off <<= 1)
            pq += __shfl_xor(pq, off, 64);
        const float alpha = rz / pq;

        float rzn = 0.f;
        for (int r = l; r < KD; r += 64) {
            const float pvv = p[r * 8 + w];
            const float qvv = q[r * 8 + w];
            xv[r * 9 + w] = fmaf(alpha, pvv, xv[r * 9 + w]);
            const float rnew = fmaf(-alpha, qvv, rv[r * 9 + w]);
            rv[r * 9 + w] = rnew;
            rzn = fmaf(rnew * rnew, dinv[w * KD + r], rzn);
        }
        #pragma unroll
        for (int off = 1; off < 64; off <<= 1)
            rzn += __shfl_xor(rzn, off, 64);
        const float beta = rzn / rz;
        rz = rzn;

        for (int r = l; r < KD; r += 64) {
            const float z = rv[r * 9 + w] * dinv[w * KD + r];
            p[r * 8 + w] = fmaf(beta, p[r * 8 + w], z);
        }
    }
    __syncthreads();

    // ---- store: out[b, i0+w, :] ----
    float* Orow = out + (size_t)(bK + i0 + w) * KD;
    for (int r = l; r < KD; r += 64)
        Orow[r] = xv[r * 9 + w];
}

extern "C" void kernel_launch(void* const* d_in, const int* in_sizes, int n_in,
                              void* d_out, int out_size, void* d_ws, size_t ws_size,
                              hipStream_t stream) {
    const float* A  = (const float*)d_in[0];
    const float* B  = (const float*)d_in[1];
    const float* ex = (const float*)d_in[2];
    const float* ey = (const float*)d_in[3];
    float* out = (float*)d_out;

    float* G = (float*)d_ws;
    float* R = G + 8 * KD * KD;

    dim3 grid1(7, 7, 16);
    gemm_gr_kernel<<<grid1, 256, 0, stream>>>(A, B, G, R);

    cg_kernel<<<200, 512, 0, stream>>>(G, R, ex, ey, out);
}